// Round 1
// baseline (455.556 us; speedup 1.0000x reference)
//
#include <hip/hip_runtime.h>
#include <hip/hip_bf16.h>

#define IN_DIM 128
#define HEADS 4
#define HEAD_DIM 32

// ---------------------------------------------------------------------------
// K1: fused qkv GEMM.  q = x@Wt, k = x@Ws, v = x@Wc.  W stored (in, out).
// Block: 256 threads, tile = 64 rows x 128 cols, blockIdx.y selects matrix.
// xT staged transposed in LDS (conflict-free: lanes write consecutive r).
// Thread tile: 8 rows x 4 cols -> W read as one coalesced float4 per i.
// ---------------------------------------------------------------------------
__global__ __launch_bounds__(256) void qkv_gemm_kernel(
    const float* __restrict__ x,
    const float* __restrict__ Wt, const float* __restrict__ Ws,
    const float* __restrict__ Wc,
    float* __restrict__ q, float* __restrict__ k, float* __restrict__ v,
    int N)
{
    const float* __restrict__ W;
    float* __restrict__ out;
    if (blockIdx.y == 0)      { W = Wt; out = q; }
    else if (blockIdx.y == 1) { W = Ws; out = k; }
    else                      { W = Wc; out = v; }

    const int r0 = blockIdx.x * 64;
    const int t  = threadIdx.x;

    __shared__ float xT[128][64];   // xT[i][r] = x[r0+r][i], 32 KB

    // load: 2048 float4 total, 8 per thread; r = idx&63 constant per lane
    #pragma unroll
    for (int it = 0; it < 8; it++) {
        int idx = t + it * 256;          // 0..2047
        int r   = idx & 63;
        int i4  = idx >> 6;              // 0..31
        float4 xv = make_float4(0.f, 0.f, 0.f, 0.f);
        if (r0 + r < N)
            xv = *(const float4*)(x + (size_t)(r0 + r) * 128 + i4 * 4);
        xT[i4 * 4 + 0][r] = xv.x;
        xT[i4 * 4 + 1][r] = xv.y;
        xT[i4 * 4 + 2][r] = xv.z;
        xT[i4 * 4 + 3][r] = xv.w;
    }
    __syncthreads();

    const int rg = t >> 5;    // 0..7  -> rows rg*8 .. rg*8+7
    const int cg = t & 31;    // 0..31 -> cols cg*4 .. cg*4+3

    float acc[8][4];
    #pragma unroll
    for (int a = 0; a < 8; a++)
        #pragma unroll
        for (int b = 0; b < 4; b++) acc[a][b] = 0.f;

    #pragma unroll 4
    for (int i = 0; i < 128; i++) {
        float4 wv = *(const float4*)(W + (size_t)i * 128 + cg * 4);
        float4 xa = *(const float4*)(&xT[i][rg * 8]);
        float4 xb = *(const float4*)(&xT[i][rg * 8 + 4]);
        float xr[8] = { xa.x, xa.y, xa.z, xa.w, xb.x, xb.y, xb.z, xb.w };
        #pragma unroll
        for (int a = 0; a < 8; a++) {
            acc[a][0] = fmaf(xr[a], wv.x, acc[a][0]);
            acc[a][1] = fmaf(xr[a], wv.y, acc[a][1]);
            acc[a][2] = fmaf(xr[a], wv.z, acc[a][2]);
            acc[a][3] = fmaf(xr[a], wv.w, acc[a][3]);
        }
    }

    #pragma unroll
    for (int a = 0; a < 8; a++) {
        int row = r0 + rg * 8 + a;
        if (row < N)
            *(float4*)(out + (size_t)row * 128 + cg * 4) =
                make_float4(acc[a][0], acc[a][1], acc[a][2], acc[a][3]);
    }
}

// ---------------------------------------------------------------------------
// K4: out = relu(agg @ Wout + bout) + x.  Same tile structure as K1.
// ---------------------------------------------------------------------------
__global__ __launch_bounds__(256) void out_gemm_kernel(
    const float* __restrict__ agg, const float* __restrict__ Wout,
    const float* __restrict__ bout, const float* __restrict__ x,
    float* __restrict__ out, int N)
{
    const int r0 = blockIdx.x * 64;
    const int t  = threadIdx.x;

    __shared__ float xT[128][64];

    #pragma unroll
    for (int it = 0; it < 8; it++) {
        int idx = t + it * 256;
        int r   = idx & 63;
        int i4  = idx >> 6;
        float4 xv = make_float4(0.f, 0.f, 0.f, 0.f);
        if (r0 + r < N)
            xv = *(const float4*)(agg + (size_t)(r0 + r) * 128 + i4 * 4);
        xT[i4 * 4 + 0][r] = xv.x;
        xT[i4 * 4 + 1][r] = xv.y;
        xT[i4 * 4 + 2][r] = xv.z;
        xT[i4 * 4 + 3][r] = xv.w;
    }
    __syncthreads();

    const int rg = t >> 5;
    const int cg = t & 31;

    float acc[8][4];
    #pragma unroll
    for (int a = 0; a < 8; a++)
        #pragma unroll
        for (int b = 0; b < 4; b++) acc[a][b] = 0.f;

    #pragma unroll 4
    for (int i = 0; i < 128; i++) {
        float4 wv = *(const float4*)(Wout + (size_t)i * 128 + cg * 4);
        float4 xa = *(const float4*)(&xT[i][rg * 8]);
        float4 xb = *(const float4*)(&xT[i][rg * 8 + 4]);
        float xr[8] = { xa.x, xa.y, xa.z, xa.w, xb.x, xb.y, xb.z, xb.w };
        #pragma unroll
        for (int a = 0; a < 8; a++) {
            acc[a][0] = fmaf(xr[a], wv.x, acc[a][0]);
            acc[a][1] = fmaf(xr[a], wv.y, acc[a][1]);
            acc[a][2] = fmaf(xr[a], wv.z, acc[a][2]);
            acc[a][3] = fmaf(xr[a], wv.w, acc[a][3]);
        }
    }

    float4 bv = *(const float4*)(bout + cg * 4);
    #pragma unroll
    for (int a = 0; a < 8; a++) {
        int row = r0 + rg * 8 + a;
        if (row < N) {
            float4 xv = *(const float4*)(x + (size_t)row * 128 + cg * 4);
            float4 o;
            o.x = fmaxf(acc[a][0] + bv.x, 0.f) + xv.x;
            o.y = fmaxf(acc[a][1] + bv.y, 0.f) + xv.y;
            o.z = fmaxf(acc[a][2] + bv.z, 0.f) + xv.z;
            o.w = fmaxf(acc[a][3] + bv.w, 0.f) + xv.w;
            *(float4*)(out + (size_t)row * 128 + cg * 4) = o;
        }
    }
}

// ---------------------------------------------------------------------------
// CSR build: degree count -> single-block scan -> fill
// ---------------------------------------------------------------------------
__global__ void degree_kernel(const int* __restrict__ edge, int E,
                              int* __restrict__ deg)
{
    int e = blockIdx.x * 256 + threadIdx.x;
    if (e < E) atomicAdd(&deg[edge[E + e]], 1);
}

__global__ __launch_bounds__(1024) void scan_kernel(
    const int* __restrict__ deg, int* __restrict__ rowptr, int N)
{
    __shared__ int wsum[16];
    const int t = threadIdx.x, lane = t & 63, wid = t >> 6;
    int running = 0;
    for (int base = 0; base < N; base += 1024) {
        int i = base + t;
        int val = (i < N) ? deg[i] : 0;
        int s = val;
        #pragma unroll
        for (int off = 1; off < 64; off <<= 1) {
            int n = __shfl_up(s, off);
            if (lane >= off) s += n;
        }
        if (lane == 63) wsum[wid] = s;
        __syncthreads();
        if (wid == 0) {
            int ws = (lane < 16) ? wsum[lane] : 0;
            #pragma unroll
            for (int off = 1; off < 16; off <<= 1) {
                int n = __shfl_up(ws, off);
                if (lane >= off) ws += n;
            }
            if (lane < 16) wsum[lane] = ws;
        }
        __syncthreads();
        int woff = (wid > 0) ? wsum[wid - 1] : 0;
        if (i < N) rowptr[i + 1] = running + woff + s;
        running += wsum[15];
        __syncthreads();
    }
    if (t == 0) rowptr[0] = 0;
}

__global__ void fill_kernel(const int* __restrict__ edge, int E,
                            const int* __restrict__ rowptr,
                            int* __restrict__ cnt, int* __restrict__ col)
{
    int e = blockIdx.x * 256 + threadIdx.x;
    if (e < E) {
        int dst = edge[E + e];
        int src = edge[e];
        int pos = atomicAdd(&cnt[dst], 1);
        col[rowptr[dst] + pos] = src;
    }
}

// ---------------------------------------------------------------------------
// K3: per-dst fused attention.  One wave-64 block per dst node.
// Lane task map: h = lane&3, edge-offset eo = lane>>2 (16 edges/chunk).
// Pass 1: scores -> ws (coalesced), running max per head (shfl_xor 4/8/16/32).
// Pass 2: e = exp(s-m); denom = sum(e); acc = sum(e * v[src]); agg = acc/denom.
// No float atomics anywhere.
// ---------------------------------------------------------------------------
__global__ __launch_bounds__(64) void attn_kernel(
    const float* __restrict__ q, const float* __restrict__ k,
    const float* __restrict__ v,
    const int* __restrict__ rowptr, const int* __restrict__ col,
    float* __restrict__ scores, float* __restrict__ agg, int N)
{
    const int dst  = blockIdx.x;
    const int lane = threadIdx.x;
    const int start = rowptr[dst];
    const int deg   = rowptr[dst + 1] - start;

    __shared__ float qs[128];
    __shared__ float sden[4];
    qs[lane]      = q[(size_t)dst * 128 + lane];
    qs[lane + 64] = q[(size_t)dst * 128 + 64 + lane];
    __syncthreads();

    if (deg == 0) {
        agg[(size_t)dst * 128 + lane] = 0.f;
        agg[(size_t)dst * 128 + 64 + lane] = 0.f;
        return;
    }

    const int h  = lane & 3;
    const int eo = lane >> 2;
    const int hsel = lane >> 5;   // head of dim `lane` (0/1); dim 64+lane -> 2+hsel

    float4 qr[8];
    #pragma unroll
    for (int j = 0; j < 8; j++)
        qr[j] = *(const float4*)(qs + h * HEAD_DIM + j * 4);

    // ---- pass 1: scores + per-head max ----
    float m = -3.4e38f;
    for (int base = 0; base < deg; base += 16) {
        int le = base + eo;
        float s = -3.4e38f;
        if (le < deg) {
            int src = col[start + le];
            const float4* kp = (const float4*)(k + (size_t)src * 128 + h * HEAD_DIM);
            float a = 0.f;
            #pragma unroll
            for (int j = 0; j < 8; j++) {
                float4 kv = kp[j];
                a = fmaf(qr[j].x, kv.x, a);
                a = fmaf(qr[j].y, kv.y, a);
                a = fmaf(qr[j].z, kv.z, a);
                a = fmaf(qr[j].w, kv.w, a);
            }
            s = a;
            scores[(size_t)(start + le) * 4 + h] = a;   // addr = (start+base)*4 + lane
        }
        m = fmaxf(m, s);
    }
    #pragma unroll
    for (int off = 4; off < 64; off <<= 1)
        m = fmaxf(m, __shfl_xor(m, off));

    // ---- pass 2: exp, denom, weighted v accumulation ----
    float dsum = 0.f, acc0 = 0.f, acc1 = 0.f;
    for (int base = 0; base < deg; base += 16) {
        int le = base + eo;
        float ev = 0.f;
        int srcreg = 0;
        if (le < deg) {
            float s = scores[(size_t)(start + le) * 4 + h];
            ev = __expf(s - m);
            srcreg = col[start + le];
        }
        dsum += ev;
        int nle = min(16, deg - base);
        for (int j = 0; j < nle; j++) {
            int   sj = __shfl(srcreg, j * 4);
            float w0 = __shfl(ev, j * 4 + hsel);
            float w1 = __shfl(ev, j * 4 + 2 + hsel);
            const float* vp = v + (size_t)sj * 128;
            acc0 = fmaf(w0, vp[lane], acc0);
            acc1 = fmaf(w1, vp[64 + lane], acc1);
        }
    }
    #pragma unroll
    for (int off = 4; off < 64; off <<= 1)
        dsum += __shfl_xor(dsum, off);
    if (lane < 4) sden[lane] = dsum;
    __syncthreads();

    float d0 = sden[hsel];
    float d1 = sden[2 + hsel];
    agg[(size_t)dst * 128 + lane]      = acc0 / d0;
    agg[(size_t)dst * 128 + 64 + lane] = acc1 / d1;
}

// ---------------------------------------------------------------------------
extern "C" void kernel_launch(void* const* d_in, const int* in_sizes, int n_in,
                              void* d_out, int out_size, void* d_ws, size_t ws_size,
                              hipStream_t stream)
{
    const float* x    = (const float*)d_in[0];
    const int*   edge = (const int*)d_in[1];   // [2, E] int
    const float* Wt   = (const float*)d_in[2];
    const float* Ws   = (const float*)d_in[3];
    const float* Wc   = (const float*)d_in[4];
    const float* Wout = (const float*)d_in[5];
    const float* bout = (const float*)d_in[6];
    float* out = (float*)d_out;

    const int N = in_sizes[0] / IN_DIM;
    const int E = in_sizes[1] / 2;

    // workspace layout (floats then ints)
    float* ws     = (float*)d_ws;
    float* q      = ws;
    float* k      = q   + (size_t)N * 128;
    float* v      = k   + (size_t)N * 128;
    float* agg    = v   + (size_t)N * 128;
    float* scores = agg + (size_t)N * 128;
    int*   rowptr = (int*)(scores + (size_t)E * 4);
    int*   deg    = rowptr + (N + 1);
    int*   cnt    = deg + N;
    int*   colb   = cnt + N;

    hipMemsetAsync(deg, 0, (size_t)N * sizeof(int), stream);
    hipMemsetAsync(cnt, 0, (size_t)N * sizeof(int), stream);

    const int gR = (N + 63) / 64;
    const int gE = (E + 255) / 256;

    qkv_gemm_kernel<<<dim3(gR, 3), 256, 0, stream>>>(x, Wt, Ws, Wc, q, k, v, N);
    degree_kernel<<<gE, 256, 0, stream>>>(edge, E, deg);
    scan_kernel<<<1, 1024, 0, stream>>>(deg, rowptr, N);
    fill_kernel<<<gE, 256, 0, stream>>>(edge, E, rowptr, cnt, colb);
    attn_kernel<<<N, 64, 0, stream>>>(q, k, v, rowptr, colb, scores, agg, N);
    out_gemm_kernel<<<gR, 256, 0, stream>>>(agg, Wout, bout, x, out, N);
}

// Round 2
// 387.552 us; speedup vs baseline: 1.1755x; 1.1755x over previous
//
#include <hip/hip_runtime.h>
#include <hip/hip_bf16.h>

#define IN_DIM 128
#define HEADS 4
#define HEAD_DIM 32

// ---------------------------------------------------------------------------
// K1: fused qkv GEMM.  q = x@Wt, k = x@Ws, v = x@Wc.  W stored (in, out).
// Block: 256 threads, tile = 64 rows x 128 cols, blockIdx.y selects matrix.
// ---------------------------------------------------------------------------
__global__ __launch_bounds__(256) void qkv_gemm_kernel(
    const float* __restrict__ x,
    const float* __restrict__ Wt, const float* __restrict__ Ws,
    const float* __restrict__ Wc,
    float* __restrict__ q, float* __restrict__ k, float* __restrict__ v,
    int N)
{
    const float* __restrict__ W;
    float* __restrict__ out;
    if (blockIdx.y == 0)      { W = Wt; out = q; }
    else if (blockIdx.y == 1) { W = Ws; out = k; }
    else                      { W = Wc; out = v; }

    const int r0 = blockIdx.x * 64;
    const int t  = threadIdx.x;

    __shared__ float xT[128][64];   // xT[i][r] = x[r0+r][i], 32 KB

    #pragma unroll
    for (int it = 0; it < 8; it++) {
        int idx = t + it * 256;
        int r   = idx & 63;
        int i4  = idx >> 6;
        float4 xv = make_float4(0.f, 0.f, 0.f, 0.f);
        if (r0 + r < N)
            xv = *(const float4*)(x + (size_t)(r0 + r) * 128 + i4 * 4);
        xT[i4 * 4 + 0][r] = xv.x;
        xT[i4 * 4 + 1][r] = xv.y;
        xT[i4 * 4 + 2][r] = xv.z;
        xT[i4 * 4 + 3][r] = xv.w;
    }
    __syncthreads();

    const int rg = t >> 5;
    const int cg = t & 31;

    float acc[8][4];
    #pragma unroll
    for (int a = 0; a < 8; a++)
        #pragma unroll
        for (int b = 0; b < 4; b++) acc[a][b] = 0.f;

    #pragma unroll 4
    for (int i = 0; i < 128; i++) {
        float4 wv = *(const float4*)(W + (size_t)i * 128 + cg * 4);
        float4 xa = *(const float4*)(&xT[i][rg * 8]);
        float4 xb = *(const float4*)(&xT[i][rg * 8 + 4]);
        float xr[8] = { xa.x, xa.y, xa.z, xa.w, xb.x, xb.y, xb.z, xb.w };
        #pragma unroll
        for (int a = 0; a < 8; a++) {
            acc[a][0] = fmaf(xr[a], wv.x, acc[a][0]);
            acc[a][1] = fmaf(xr[a], wv.y, acc[a][1]);
            acc[a][2] = fmaf(xr[a], wv.z, acc[a][2]);
            acc[a][3] = fmaf(xr[a], wv.w, acc[a][3]);
        }
    }

    #pragma unroll
    for (int a = 0; a < 8; a++) {
        int row = r0 + rg * 8 + a;
        if (row < N)
            *(float4*)(out + (size_t)row * 128 + cg * 4) =
                make_float4(acc[a][0], acc[a][1], acc[a][2], acc[a][3]);
    }
}

// ---------------------------------------------------------------------------
// K4: out = relu(agg @ Wout + bout) + x.
// ---------------------------------------------------------------------------
__global__ __launch_bounds__(256) void out_gemm_kernel(
    const float* __restrict__ agg, const float* __restrict__ Wout,
    const float* __restrict__ bout, const float* __restrict__ x,
    float* __restrict__ out, int N)
{
    const int r0 = blockIdx.x * 64;
    const int t  = threadIdx.x;

    __shared__ float xT[128][64];

    #pragma unroll
    for (int it = 0; it < 8; it++) {
        int idx = t + it * 256;
        int r   = idx & 63;
        int i4  = idx >> 6;
        float4 xv = make_float4(0.f, 0.f, 0.f, 0.f);
        if (r0 + r < N)
            xv = *(const float4*)(agg + (size_t)(r0 + r) * 128 + i4 * 4);
        xT[i4 * 4 + 0][r] = xv.x;
        xT[i4 * 4 + 1][r] = xv.y;
        xT[i4 * 4 + 2][r] = xv.z;
        xT[i4 * 4 + 3][r] = xv.w;
    }
    __syncthreads();

    const int rg = t >> 5;
    const int cg = t & 31;

    float acc[8][4];
    #pragma unroll
    for (int a = 0; a < 8; a++)
        #pragma unroll
        for (int b = 0; b < 4; b++) acc[a][b] = 0.f;

    #pragma unroll 4
    for (int i = 0; i < 128; i++) {
        float4 wv = *(const float4*)(Wout + (size_t)i * 128 + cg * 4);
        float4 xa = *(const float4*)(&xT[i][rg * 8]);
        float4 xb = *(const float4*)(&xT[i][rg * 8 + 4]);
        float xr[8] = { xa.x, xa.y, xa.z, xa.w, xb.x, xb.y, xb.z, xb.w };
        #pragma unroll
        for (int a = 0; a < 8; a++) {
            acc[a][0] = fmaf(xr[a], wv.x, acc[a][0]);
            acc[a][1] = fmaf(xr[a], wv.y, acc[a][1]);
            acc[a][2] = fmaf(xr[a], wv.z, acc[a][2]);
            acc[a][3] = fmaf(xr[a], wv.w, acc[a][3]);
        }
    }

    float4 bv = *(const float4*)(bout + cg * 4);
    #pragma unroll
    for (int a = 0; a < 8; a++) {
        int row = r0 + rg * 8 + a;
        if (row < N) {
            float4 xv = *(const float4*)(x + (size_t)row * 128 + cg * 4);
            float4 o;
            o.x = fmaxf(acc[a][0] + bv.x, 0.f) + xv.x;
            o.y = fmaxf(acc[a][1] + bv.y, 0.f) + xv.y;
            o.z = fmaxf(acc[a][2] + bv.z, 0.f) + xv.z;
            o.w = fmaxf(acc[a][3] + bv.w, 0.f) + xv.w;
            *(float4*)(out + (size_t)row * 128 + cg * 4) = o;
        }
    }
}

// ---------------------------------------------------------------------------
// CSR build: degree -> multi-block scan (local, bsum, fixup) -> fill
// ---------------------------------------------------------------------------
__global__ void degree_kernel(const int* __restrict__ edge, int E,
                              int* __restrict__ deg)
{
    int e = blockIdx.x * 256 + threadIdx.x;
    if (e < E) atomicAdd(&deg[edge[E + e]], 1);
}

// block handles 1024 elements (256 threads x int4); writes block-local
// inclusive scan to locscan and block total to bsum[blockIdx].
__global__ __launch_bounds__(256) void scan_local_kernel(
    const int* __restrict__ deg, int* __restrict__ locscan,
    int* __restrict__ bsum, int N)
{
    const int t = threadIdx.x, lane = t & 63, wid = t >> 6;
    const int i0 = blockIdx.x * 1024 + t * 4;
    __shared__ int wtot[4];

    int d0 = 0, d1 = 0, d2 = 0, d3 = 0;
    if (i0 + 3 < N) {
        int4 dv = *(const int4*)(deg + i0);
        d0 = dv.x; d1 = dv.y; d2 = dv.z; d3 = dv.w;
    } else {
        if (i0 < N)     d0 = deg[i0];
        if (i0 + 1 < N) d1 = deg[i0 + 1];
        if (i0 + 2 < N) d2 = deg[i0 + 2];
        if (i0 + 3 < N) d3 = deg[i0 + 3];
    }
    int s1 = d0 + d1, s2 = s1 + d2, s3 = s2 + d3;
    int tot = s3;

    int sc = tot;
    #pragma unroll
    for (int off = 1; off < 64; off <<= 1) {
        int n = __shfl_up(sc, off);
        if (lane >= off) sc += n;
    }
    if (lane == 63) wtot[wid] = sc;
    __syncthreads();

    int wof = 0;
    #pragma unroll
    for (int w = 0; w < 4; w++) wof += (w < wid) ? wtot[w] : 0;
    int pref = wof + sc - tot;     // exclusive prefix for this thread

    if (i0 < N)     locscan[i0]     = pref + d0;
    if (i0 + 1 < N) locscan[i0 + 1] = pref + s1;
    if (i0 + 2 < N) locscan[i0 + 2] = pref + s2;
    if (i0 + 3 < N) locscan[i0 + 3] = pref + s3;
    if (t == 0) bsum[blockIdx.x] = wtot[0] + wtot[1] + wtot[2] + wtot[3];
}

// single wave: in-place exclusive scan of nb block sums
__global__ __launch_bounds__(64) void scan_bsum_kernel(int* __restrict__ bsum,
                                                       int nb)
{
    const int lane = threadIdx.x;
    int run = 0;
    for (int b = 0; b < nb; b += 64) {
        int v = (b + lane < nb) ? bsum[b + lane] : 0;
        int sc = v;
        #pragma unroll
        for (int off = 1; off < 64; off <<= 1) {
            int n = __shfl_up(sc, off);
            if (lane >= off) sc += n;
        }
        if (b + lane < nb) bsum[b + lane] = run + sc - v;
        run += __shfl(sc, 63);
    }
}

__global__ void scan_final_kernel(const int* __restrict__ locscan,
                                  const int* __restrict__ bsum,
                                  int* __restrict__ rowptr, int N)
{
    int i = blockIdx.x * 256 + threadIdx.x;
    if (i < N) rowptr[i + 1] = locscan[i] + bsum[i >> 10];
    if (i == 0) rowptr[0] = 0;
}

__global__ void fill_kernel(const int* __restrict__ edge, int E,
                            const int* __restrict__ rowptr,
                            int* __restrict__ cnt, int* __restrict__ col)
{
    int e = blockIdx.x * 256 + threadIdx.x;
    if (e < E) {
        int dst = edge[E + e];
        int src = edge[e];
        int pos = atomicAdd(&cnt[dst], 1);
        col[rowptr[dst] + pos] = src;
    }
}

// ---------------------------------------------------------------------------
// v-accumulation over one chunk of <=16 edges; weights/srcs broadcast via
// LDS (no shfl dependency chain) -> full unroll -> 32 global loads in flight.
// ---------------------------------------------------------------------------
__device__ __forceinline__ void vacc_chunk(const float* __restrict__ v,
                                           const int* esrc, const float* ew,
                                           int lane, int hsel, int nle,
                                           float& acc0, float& acc1)
{
    if (nle == 16) {
        #pragma unroll
        for (int j = 0; j < 16; j++) {
            int   sj = esrc[j];
            float w0 = ew[j * 4 + hsel];
            float w1 = ew[j * 4 + 2 + hsel];
            const float* vp = v + (size_t)sj * 128;
            acc0 = fmaf(w0, vp[lane], acc0);
            acc1 = fmaf(w1, vp[64 + lane], acc1);
        }
    } else {
        for (int j = 0; j < nle; j++) {
            int   sj = esrc[j];
            float w0 = ew[j * 4 + hsel];
            float w1 = ew[j * 4 + 2 + hsel];
            const float* vp = v + (size_t)sj * 128;
            acc0 = fmaf(w0, vp[lane], acc0);
            acc1 = fmaf(w1, vp[64 + lane], acc1);
        }
    }
}

// ---------------------------------------------------------------------------
// K3: per-dst fused attention.  One wave-64 block per dst node.
// h = lane&3, eo = lane>>2 (16 edges/chunk).  deg<=64 fast path keeps
// scores + src indices in registers (no global scores traffic).
// ---------------------------------------------------------------------------
__global__ __launch_bounds__(64) void attn_kernel(
    const float* __restrict__ q, const float* __restrict__ k,
    const float* __restrict__ v,
    const int* __restrict__ rowptr, const int* __restrict__ col,
    float* __restrict__ scores, float* __restrict__ agg, int N)
{
    const int dst  = blockIdx.x;
    const int lane = threadIdx.x;
    const int start = rowptr[dst];
    const int deg   = rowptr[dst + 1] - start;

    __shared__ float qs[128];
    __shared__ float ew[64];
    __shared__ int   esrc[16];

    const size_t orow = (size_t)dst * 128;
    qs[lane]      = q[orow + lane];
    qs[lane + 64] = q[orow + 64 + lane];
    __syncthreads();

    if (deg == 0) {
        agg[orow + lane] = 0.f;
        agg[orow + 64 + lane] = 0.f;
        return;
    }

    const int h    = lane & 3;
    const int eo   = lane >> 2;
    const int hsel = lane >> 5;

    float4 qr[8];
    #pragma unroll
    for (int j = 0; j < 8; j++)
        qr[j] = *(const float4*)(qs + h * HEAD_DIM + j * 4);

    float m = -3.4e38f, dsum = 0.f, acc0 = 0.f, acc1 = 0.f;

    if (deg <= 64) {
        // ---- fast path: scores & srcs live in registers ----
        float sreg[4]; int creg[4];
        #pragma unroll
        for (int c = 0; c < 4; c++) {
            sreg[c] = -3.4e38f; creg[c] = 0;
            if (c * 16 < deg) {                 // uniform branch
                int le = c * 16 + eo;
                if (le < deg) {
                    int src = col[start + le];
                    creg[c] = src;
                    const float4* kp = (const float4*)(k + (size_t)src * 128 + h * HEAD_DIM);
                    float a = 0.f;
                    #pragma unroll
                    for (int j = 0; j < 8; j++) {
                        float4 kv = kp[j];
                        a = fmaf(qr[j].x, kv.x, a);
                        a = fmaf(qr[j].y, kv.y, a);
                        a = fmaf(qr[j].z, kv.z, a);
                        a = fmaf(qr[j].w, kv.w, a);
                    }
                    sreg[c] = a;
                }
                m = fmaxf(m, sreg[c]);
            }
        }
        #pragma unroll
        for (int off = 4; off < 64; off <<= 1)
            m = fmaxf(m, __shfl_xor(m, off));

        #pragma unroll
        for (int c = 0; c < 4; c++) {
            if (c * 16 < deg) {                 // uniform branch
                int le = c * 16 + eo;
                float ev = (le < deg) ? __expf(sreg[c] - m) : 0.f;
                dsum += ev;
                ew[lane] = ev;
                if (h == 0) esrc[eo] = creg[c];
                __syncthreads();
                vacc_chunk(v, esrc, ew, lane, hsel, min(16, deg - c * 16), acc0, acc1);
                __syncthreads();
            }
        }
    } else {
        // ---- general path: scores round-trip through global ----
        for (int base = 0; base < deg; base += 16) {
            int le = base + eo;
            float s = -3.4e38f;
            if (le < deg) {
                int src = col[start + le];
                const float4* kp = (const float4*)(k + (size_t)src * 128 + h * HEAD_DIM);
                float a = 0.f;
                #pragma unroll
                for (int j = 0; j < 8; j++) {
                    float4 kv = kp[j];
                    a = fmaf(qr[j].x, kv.x, a);
                    a = fmaf(qr[j].y, kv.y, a);
                    a = fmaf(qr[j].z, kv.z, a);
                    a = fmaf(qr[j].w, kv.w, a);
                }
                s = a;
                scores[(size_t)(start + le) * 4 + h] = a;
            }
            m = fmaxf(m, s);
        }
        #pragma unroll
        for (int off = 4; off < 64; off <<= 1)
            m = fmaxf(m, __shfl_xor(m, off));

        for (int base = 0; base < deg; base += 16) {
            int le = base + eo;
            float ev = 0.f; int src = 0;
            if (le < deg) {
                ev  = __expf(scores[(size_t)(start + le) * 4 + h] - m);
                src = col[start + le];
            }
            dsum += ev;
            ew[lane] = ev;
            if (h == 0) esrc[eo] = src;
            __syncthreads();
            vacc_chunk(v, esrc, ew, lane, hsel, min(16, deg - base), acc0, acc1);
            __syncthreads();
        }
    }

    #pragma unroll
    for (int off = 4; off < 64; off <<= 1)
        dsum += __shfl_xor(dsum, off);
    float d0 = __shfl(dsum, hsel);
    float d1 = __shfl(dsum, 2 + hsel);
    agg[orow + lane]      = acc0 / d0;
    agg[orow + 64 + lane] = acc1 / d1;
}

// ---------------------------------------------------------------------------
extern "C" void kernel_launch(void* const* d_in, const int* in_sizes, int n_in,
                              void* d_out, int out_size, void* d_ws, size_t ws_size,
                              hipStream_t stream)
{
    const float* x    = (const float*)d_in[0];
    const int*   edge = (const int*)d_in[1];   // [2, E] int
    const float* Wt   = (const float*)d_in[2];
    const float* Ws   = (const float*)d_in[3];
    const float* Wc   = (const float*)d_in[4];
    const float* Wout = (const float*)d_in[5];
    const float* bout = (const float*)d_in[6];
    float* out = (float*)d_out;

    const int N = in_sizes[0] / IN_DIM;
    const int E = in_sizes[1] / 2;

    // workspace layout (floats then ints; keep int4 alignment for deg)
    float* ws     = (float*)d_ws;
    float* q      = ws;
    float* k      = q   + (size_t)N * 128;
    float* v      = k   + (size_t)N * 128;
    float* agg    = v   + (size_t)N * 128;
    float* scores = agg + (size_t)N * 128;
    int*   rowptr = (int*)(scores + (size_t)E * 4);
    int*   deg    = rowptr + ((N + 1 + 3) & ~3);   // 16B aligned
    int*   cnt    = deg + N;
    int*   locscan= cnt + N;
    int*   bsum   = locscan + N;
    int*   colb   = bsum + 1024;

    hipMemsetAsync(deg, 0, (size_t)N * sizeof(int), stream);
    hipMemsetAsync(cnt, 0, (size_t)N * sizeof(int), stream);

    const int gR   = (N + 63) / 64;
    const int gE   = (E + 255) / 256;
    const int nb1k = (N + 1023) / 1024;

    qkv_gemm_kernel<<<dim3(gR, 3), 256, 0, stream>>>(x, Wt, Ws, Wc, q, k, v, N);
    degree_kernel<<<gE, 256, 0, stream>>>(edge, E, deg);
    scan_local_kernel<<<nb1k, 256, 0, stream>>>(deg, locscan, bsum, N);
    scan_bsum_kernel<<<1, 64, 0, stream>>>(bsum, nb1k);
    scan_final_kernel<<<(N + 255) / 256, 256, 0, stream>>>(locscan, bsum, rowptr, N);
    fill_kernel<<<gE, 256, 0, stream>>>(edge, E, rowptr, cnt, colb);
    attn_kernel<<<N, 64, 0, stream>>>(q, k, v, rowptr, colb, scores, agg, N);
    out_gemm_kernel<<<gR, 256, 0, stream>>>(agg, Wout, bout, x, out, N);
}

// Round 3
// 368.949 us; speedup vs baseline: 1.2347x; 1.0504x over previous
//
#include <hip/hip_runtime.h>
#include <hip/hip_bf16.h>

#define IN_DIM 128
#define HEADS 4
#define HEAD_DIM 32

// float -> bf16 (RNE)
__device__ __forceinline__ unsigned short f2bf(float f) {
    unsigned u = __float_as_uint(f);
    u += 0x7fffu + ((u >> 16) & 1u);
    return (unsigned short)(u >> 16);
}
// one uint32 holding bf16 pair {elem 2i (lo16), elem 2i+1 (hi16)} -> floats
__device__ __forceinline__ float2 bf2f(unsigned u) {
    return make_float2(__uint_as_float(u << 16),
                       __uint_as_float(u & 0xffff0000u));
}

// ---------------------------------------------------------------------------
// K1: fused qkv GEMM.  q = x@Wt (fp32), k = x@Ws (bf16), v = x@Wc (bf16).
// One block: 64 rows, x staged once in LDS, all 3 matrices computed.
// ---------------------------------------------------------------------------
__global__ __launch_bounds__(256) void qkv_gemm_kernel(
    const float* __restrict__ x,
    const float* __restrict__ Wt, const float* __restrict__ Ws,
    const float* __restrict__ Wc,
    float* __restrict__ q, unsigned short* __restrict__ kh,
    unsigned short* __restrict__ vh, int N)
{
    const int r0 = blockIdx.x * 64;
    const int t  = threadIdx.x;

    __shared__ float xT[128][64];   // xT[i][r] = x[r0+r][i], 32 KB

    #pragma unroll
    for (int it = 0; it < 8; it++) {
        int idx = t + it * 256;
        int r   = idx & 63;
        int i4  = idx >> 6;
        float4 xv = make_float4(0.f, 0.f, 0.f, 0.f);
        if (r0 + r < N)
            xv = *(const float4*)(x + (size_t)(r0 + r) * 128 + i4 * 4);
        xT[i4 * 4 + 0][r] = xv.x;
        xT[i4 * 4 + 1][r] = xv.y;
        xT[i4 * 4 + 2][r] = xv.z;
        xT[i4 * 4 + 3][r] = xv.w;
    }
    __syncthreads();

    const int rg = t >> 5;    // 0..7 -> rows rg*8..rg*8+7
    const int cg = t & 31;    // 0..31 -> cols cg*4..cg*4+3

    const float* Wm[3] = { Wt, Ws, Wc };

    for (int m = 0; m < 3; m++) {
        const float* __restrict__ W = Wm[m];
        float acc[8][4];
        #pragma unroll
        for (int a = 0; a < 8; a++)
            #pragma unroll
            for (int b = 0; b < 4; b++) acc[a][b] = 0.f;

        #pragma unroll 4
        for (int i = 0; i < 128; i++) {
            float4 wv = *(const float4*)(W + (size_t)i * 128 + cg * 4);
            float4 xa = *(const float4*)(&xT[i][rg * 8]);
            float4 xb = *(const float4*)(&xT[i][rg * 8 + 4]);
            float xr[8] = { xa.x, xa.y, xa.z, xa.w, xb.x, xb.y, xb.z, xb.w };
            #pragma unroll
            for (int a = 0; a < 8; a++) {
                acc[a][0] = fmaf(xr[a], wv.x, acc[a][0]);
                acc[a][1] = fmaf(xr[a], wv.y, acc[a][1]);
                acc[a][2] = fmaf(xr[a], wv.z, acc[a][2]);
                acc[a][3] = fmaf(xr[a], wv.w, acc[a][3]);
            }
        }

        if (m == 0) {
            #pragma unroll
            for (int a = 0; a < 8; a++) {
                int row = r0 + rg * 8 + a;
                if (row < N)
                    *(float4*)(q + (size_t)row * 128 + cg * 4) =
                        make_float4(acc[a][0], acc[a][1], acc[a][2], acc[a][3]);
            }
        } else {
            unsigned short* ob = (m == 1) ? kh : vh;
            #pragma unroll
            for (int a = 0; a < 8; a++) {
                int row = r0 + rg * 8 + a;
                if (row < N) {
                    ushort4 o;
                    o.x = f2bf(acc[a][0]);
                    o.y = f2bf(acc[a][1]);
                    o.z = f2bf(acc[a][2]);
                    o.w = f2bf(acc[a][3]);
                    *(ushort4*)(ob + (size_t)row * 128 + cg * 4) = o;
                }
            }
        }
    }
}

// ---------------------------------------------------------------------------
// K4: out = relu(agg @ Wout + bout) + x.
// ---------------------------------------------------------------------------
__global__ __launch_bounds__(256) void out_gemm_kernel(
    const float* __restrict__ agg, const float* __restrict__ Wout,
    const float* __restrict__ bout, const float* __restrict__ x,
    float* __restrict__ out, int N)
{
    const int r0 = blockIdx.x * 64;
    const int t  = threadIdx.x;

    __shared__ float xT[128][64];

    #pragma unroll
    for (int it = 0; it < 8; it++) {
        int idx = t + it * 256;
        int r   = idx & 63;
        int i4  = idx >> 6;
        float4 xv = make_float4(0.f, 0.f, 0.f, 0.f);
        if (r0 + r < N)
            xv = *(const float4*)(agg + (size_t)(r0 + r) * 128 + i4 * 4);
        xT[i4 * 4 + 0][r] = xv.x;
        xT[i4 * 4 + 1][r] = xv.y;
        xT[i4 * 4 + 2][r] = xv.z;
        xT[i4 * 4 + 3][r] = xv.w;
    }
    __syncthreads();

    const int rg = t >> 5;
    const int cg = t & 31;

    float acc[8][4];
    #pragma unroll
    for (int a = 0; a < 8; a++)
        #pragma unroll
        for (int b = 0; b < 4; b++) acc[a][b] = 0.f;

    #pragma unroll 4
    for (int i = 0; i < 128; i++) {
        float4 wv = *(const float4*)(Wout + (size_t)i * 128 + cg * 4);
        float4 xa = *(const float4*)(&xT[i][rg * 8]);
        float4 xb = *(const float4*)(&xT[i][rg * 8 + 4]);
        float xr[8] = { xa.x, xa.y, xa.z, xa.w, xb.x, xb.y, xb.z, xb.w };
        #pragma unroll
        for (int a = 0; a < 8; a++) {
            acc[a][0] = fmaf(xr[a], wv.x, acc[a][0]);
            acc[a][1] = fmaf(xr[a], wv.y, acc[a][1]);
            acc[a][2] = fmaf(xr[a], wv.z, acc[a][2]);
            acc[a][3] = fmaf(xr[a], wv.w, acc[a][3]);
        }
    }

    float4 bv = *(const float4*)(bout + cg * 4);
    #pragma unroll
    for (int a = 0; a < 8; a++) {
        int row = r0 + rg * 8 + a;
        if (row < N) {
            float4 xv = *(const float4*)(x + (size_t)row * 128 + cg * 4);
            float4 o;
            o.x = fmaxf(acc[a][0] + bv.x, 0.f) + xv.x;
            o.y = fmaxf(acc[a][1] + bv.y, 0.f) + xv.y;
            o.z = fmaxf(acc[a][2] + bv.z, 0.f) + xv.z;
            o.w = fmaxf(acc[a][3] + bv.w, 0.f) + xv.w;
            *(float4*)(out + (size_t)row * 128 + cg * 4) = o;
        }
    }
}

// ---------------------------------------------------------------------------
// CSR build: degree -> multi-block scan -> fill
// ---------------------------------------------------------------------------
__global__ void degree_kernel(const int* __restrict__ edge, int E,
                              int* __restrict__ deg)
{
    int e = blockIdx.x * 256 + threadIdx.x;
    if (e < E) atomicAdd(&deg[edge[E + e]], 1);
}

__global__ __launch_bounds__(256) void scan_local_kernel(
    const int* __restrict__ deg, int* __restrict__ locscan,
    int* __restrict__ bsum, int N)
{
    const int t = threadIdx.x, lane = t & 63, wid = t >> 6;
    const int i0 = blockIdx.x * 1024 + t * 4;
    __shared__ int wtot[4];

    int d0 = 0, d1 = 0, d2 = 0, d3 = 0;
    if (i0 + 3 < N) {
        int4 dv = *(const int4*)(deg + i0);
        d0 = dv.x; d1 = dv.y; d2 = dv.z; d3 = dv.w;
    } else {
        if (i0 < N)     d0 = deg[i0];
        if (i0 + 1 < N) d1 = deg[i0 + 1];
        if (i0 + 2 < N) d2 = deg[i0 + 2];
        if (i0 + 3 < N) d3 = deg[i0 + 3];
    }
    int s1 = d0 + d1, s2 = s1 + d2, s3 = s2 + d3;
    int tot = s3;

    int sc = tot;
    #pragma unroll
    for (int off = 1; off < 64; off <<= 1) {
        int n = __shfl_up(sc, off);
        if (lane >= off) sc += n;
    }
    if (lane == 63) wtot[wid] = sc;
    __syncthreads();

    int wof = 0;
    #pragma unroll
    for (int w = 0; w < 4; w++) wof += (w < wid) ? wtot[w] : 0;
    int pref = wof + sc - tot;

    if (i0 < N)     locscan[i0]     = pref + d0;
    if (i0 + 1 < N) locscan[i0 + 1] = pref + s1;
    if (i0 + 2 < N) locscan[i0 + 2] = pref + s2;
    if (i0 + 3 < N) locscan[i0 + 3] = pref + s3;
    if (t == 0) bsum[blockIdx.x] = wtot[0] + wtot[1] + wtot[2] + wtot[3];
}

__global__ __launch_bounds__(64) void scan_bsum_kernel(int* __restrict__ bsum,
                                                       int nb)
{
    const int lane = threadIdx.x;
    int run = 0;
    for (int b = 0; b < nb; b += 64) {
        int v = (b + lane < nb) ? bsum[b + lane] : 0;
        int sc = v;
        #pragma unroll
        for (int off = 1; off < 64; off <<= 1) {
            int n = __shfl_up(sc, off);
            if (lane >= off) sc += n;
        }
        if (b + lane < nb) bsum[b + lane] = run + sc - v;
        run += __shfl(sc, 63);
    }
}

__global__ void scan_final_kernel(const int* __restrict__ locscan,
                                  const int* __restrict__ bsum,
                                  int* __restrict__ rowptr, int N)
{
    int i = blockIdx.x * 256 + threadIdx.x;
    if (i < N) rowptr[i + 1] = locscan[i] + bsum[i >> 10];
    if (i == 0) rowptr[0] = 0;
}

__global__ void fill_kernel(const int* __restrict__ edge, int E,
                            const int* __restrict__ rowptr,
                            int* __restrict__ cnt, int* __restrict__ col)
{
    int e = blockIdx.x * 256 + threadIdx.x;
    if (e < E) {
        int dst = edge[E + e];
        int src = edge[e];
        int pos = atomicAdd(&cnt[dst], 1);
        col[rowptr[dst] + pos] = src;
    }
}

// q (fp32, head h) dot k-row segment (bf16, 32 elems = 4 float4)
__device__ __forceinline__ float dot_qk(const float4* __restrict__ kp,
                                        const float4* qr)
{
    float a = 0.f;
    #pragma unroll
    for (int t = 0; t < 4; t++) {
        float4 kv = kp[t];   // bf16 elems 8t..8t+7
        float2 p0 = bf2f(__float_as_uint(kv.x));
        float2 p1 = bf2f(__float_as_uint(kv.y));
        float2 p2 = bf2f(__float_as_uint(kv.z));
        float2 p3 = bf2f(__float_as_uint(kv.w));
        a = fmaf(qr[2*t].x,   p0.x, a);
        a = fmaf(qr[2*t].y,   p0.y, a);
        a = fmaf(qr[2*t].z,   p1.x, a);
        a = fmaf(qr[2*t].w,   p1.y, a);
        a = fmaf(qr[2*t+1].x, p2.x, a);
        a = fmaf(qr[2*t+1].y, p2.y, a);
        a = fmaf(qr[2*t+1].z, p3.x, a);
        a = fmaf(qr[2*t+1].w, p3.y, a);
    }
    return a;
}

// ---------------------------------------------------------------------------
// K3: per-dst fused attention.  4 dst per 256-thread block, one wave each.
// No LDS, no __syncthreads.  h = lane&3, eo = lane>>2 (16 edges/chunk).
// v-accumulation: lane owns output dims {2*lane, 2*lane+1} (head = lane>>4),
// loads one uint (bf16 pair) per edge; weights/srcs broadcast via shfl;
// inner 16-edge loop branch-free (OOB lanes carry ev=0, src=0).
// ---------------------------------------------------------------------------
__global__ __launch_bounds__(256) void attn_kernel(
    const float* __restrict__ q, const unsigned short* __restrict__ kh,
    const unsigned short* __restrict__ vh,
    const int* __restrict__ rowptr, const int* __restrict__ col,
    float* __restrict__ scores, float* __restrict__ agg, int N)
{
    const int wave = threadIdx.x >> 6;
    const int lane = threadIdx.x & 63;
    const int dst  = blockIdx.x * 4 + wave;
    if (dst >= N) return;

    const int start = rowptr[dst];
    const int deg   = rowptr[dst + 1] - start;
    const size_t orow = (size_t)dst * 128;

    if (deg == 0) {
        *(float2*)(agg + orow + 2 * lane) = make_float2(0.f, 0.f);
        return;
    }

    const int h  = lane & 3;    // head for score pass
    const int eo = lane >> 2;   // edge offset within 16-chunk
    const int hv = lane >> 4;   // head owning dims 2*lane, 2*lane+1

    float4 qr[8];
    const float4* qp = (const float4*)(q + orow + h * HEAD_DIM);
    #pragma unroll
    for (int j = 0; j < 8; j++) qr[j] = qp[j];

    float m = -3.4e38f, dsum = 0.f, acc0 = 0.f, acc1 = 0.f;

    if (deg <= 64) {
        // ---- fast path: scores & srcs in registers ----
        float sreg[4]; int creg[4];
        #pragma unroll
        for (int c = 0; c < 4; c++) {
            sreg[c] = -3.4e38f; creg[c] = 0;
            int le = c * 16 + eo;
            if (le < deg) {
                int src = col[start + le];
                creg[c] = src;
                sreg[c] = dot_qk(
                    (const float4*)(kh + (size_t)src * 128 + h * HEAD_DIM), qr);
            }
            m = fmaxf(m, sreg[c]);
        }
        #pragma unroll
        for (int off = 4; off < 64; off <<= 1)
            m = fmaxf(m, __shfl_xor(m, off));

        #pragma unroll
        for (int c = 0; c < 4; c++) {
            if (c * 16 < deg) {              // wave-uniform branch
                int le = c * 16 + eo;
                float ev = (le < deg) ? __expf(sreg[c] - m) : 0.f;
                dsum += ev;
                #pragma unroll
                for (int j = 0; j < 16; j++) {
                    int   sj = __shfl(creg[c], j * 4);
                    float w  = __shfl(ev, j * 4 + hv);
                    unsigned uv = *(const unsigned*)(vh + (size_t)sj * 128 + 2 * lane);
                    float2 vv = bf2f(uv);
                    acc0 = fmaf(w, vv.x, acc0);
                    acc1 = fmaf(w, vv.y, acc1);
                }
            }
        }
    } else {
        // ---- general path: scores round-trip through global ----
        for (int base = 0; base < deg; base += 16) {
            int le = base + eo;
            float s = -3.4e38f;
            if (le < deg) {
                int src = col[start + le];
                s = dot_qk(
                    (const float4*)(kh + (size_t)src * 128 + h * HEAD_DIM), qr);
                scores[(size_t)(start + le) * 4 + h] = s;
            }
            m = fmaxf(m, s);
        }
        #pragma unroll
        for (int off = 4; off < 64; off <<= 1)
            m = fmaxf(m, __shfl_xor(m, off));

        for (int base = 0; base < deg; base += 16) {
            int le = base + eo;
            float ev = 0.f; int src = 0;
            if (le < deg) {
                ev  = __expf(scores[(size_t)(start + le) * 4 + h] - m);
                src = col[start + le];
            }
            dsum += ev;
            #pragma unroll
            for (int j = 0; j < 16; j++) {
                int   sj = __shfl(src, j * 4);
                float w  = __shfl(ev, j * 4 + hv);
                unsigned uv = *(const unsigned*)(vh + (size_t)sj * 128 + 2 * lane);
                float2 vv = bf2f(uv);
                acc0 = fmaf(w, vv.x, acc0);
                acc1 = fmaf(w, vv.y, acc1);
            }
        }
    }

    #pragma unroll
    for (int off = 4; off < 64; off <<= 1)
        dsum += __shfl_xor(dsum, off);
    float d = __shfl(dsum, hv);      // head-hv denominator (lanes 0..3 hold heads)
    *(float2*)(agg + orow + 2 * lane) = make_float2(acc0 / d, acc1 / d);
}

// ---------------------------------------------------------------------------
extern "C" void kernel_launch(void* const* d_in, const int* in_sizes, int n_in,
                              void* d_out, int out_size, void* d_ws, size_t ws_size,
                              hipStream_t stream)
{
    const float* x    = (const float*)d_in[0];
    const int*   edge = (const int*)d_in[1];   // [2, E] int
    const float* Wt   = (const float*)d_in[2];
    const float* Ws   = (const float*)d_in[3];
    const float* Wc   = (const float*)d_in[4];
    const float* Wout = (const float*)d_in[5];
    const float* bout = (const float*)d_in[6];
    float* out = (float*)d_out;

    const int N = in_sizes[0] / IN_DIM;
    const int E = in_sizes[1] / 2;

    // workspace layout: fp32 regions, then bf16, then ints (16B-aligned each)
    float* q      = (float*)d_ws;
    float* agg    = q   + (size_t)N * 128;
    float* scores = agg + (size_t)N * 128;
    unsigned short* kh = (unsigned short*)(scores + (size_t)E * 4);
    unsigned short* vh = kh + (size_t)N * 128;
    int*   rowptr = (int*)(vh + (size_t)N * 128);
    int*   deg    = rowptr + ((N + 1 + 3) & ~3);
    int*   cnt    = deg + N;
    int*   locscan= cnt + N;
    int*   bsum   = locscan + N;
    int*   colb   = bsum + 1024;

    hipMemsetAsync(deg, 0, (size_t)N * sizeof(int), stream);
    hipMemsetAsync(cnt, 0, (size_t)N * sizeof(int), stream);

    const int gR   = (N + 63) / 64;
    const int gE   = (E + 255) / 256;
    const int nb1k = (N + 1023) / 1024;

    qkv_gemm_kernel<<<gR, 256, 0, stream>>>(x, Wt, Ws, Wc, q, kh, vh, N);
    degree_kernel<<<gE, 256, 0, stream>>>(edge, E, deg);
    scan_local_kernel<<<nb1k, 256, 0, stream>>>(deg, locscan, bsum, N);
    scan_bsum_kernel<<<1, 64, 0, stream>>>(bsum, nb1k);
    scan_final_kernel<<<(N + 255) / 256, 256, 0, stream>>>(locscan, bsum, rowptr, N);
    fill_kernel<<<gE, 256, 0, stream>>>(edge, E, rowptr, cnt, colb);
    attn_kernel<<<(N + 3) / 4, 256, 0, stream>>>(q, kh, vh, rowptr, colb, scores, agg, N);
    out_gemm_kernel<<<gR, 256, 0, stream>>>(agg, Wout, bout, x, out, N);
}

// Round 4
// 309.326 us; speedup vs baseline: 1.4727x; 1.1927x over previous
//
#include <hip/hip_runtime.h>
#include <hip/hip_bf16.h>

#define HEADS 4
#define HEAD_DIM 32

typedef __bf16 bf16x8 __attribute__((ext_vector_type(8)));
typedef float  f32x4  __attribute__((ext_vector_type(4)));
typedef _Float16 h2   __attribute__((ext_vector_type(2)));

// float -> bf16 (RNE)
__device__ __forceinline__ unsigned short f2bf(float f) {
    unsigned u = __float_as_uint(f);
    u += 0x7fffu + ((u >> 16) & 1u);
    return (unsigned short)(u >> 16);
}
// uint32 bf16 pair {elem 2i (lo16), 2i+1 (hi16)} -> floats
__device__ __forceinline__ float2 bf2f(unsigned u) {
    return make_float2(__uint_as_float(u << 16),
                       __uint_as_float(u & 0xffff0000u));
}
__device__ __forceinline__ unsigned short f2h(float f) {
    _Float16 h = (_Float16)f;
    return *(unsigned short*)&h;
}

// ---------------------------------------------------------------------------
// conv_x: fp32 -> bf16 row-major copy (8 elems/thread)
// ---------------------------------------------------------------------------
__global__ void conv_x_kernel(const float* __restrict__ x,
                              unsigned short* __restrict__ xb, long total)
{
    long i8 = (long)blockIdx.x * 256 + threadIdx.x;
    long base = i8 * 8;
    if (base + 7 < total) {
        float4 a = *(const float4*)(x + base);
        float4 b = *(const float4*)(x + base + 4);
        ushort4 lo = { f2bf(a.x), f2bf(a.y), f2bf(a.z), f2bf(a.w) };
        ushort4 hi = { f2bf(b.x), f2bf(b.y), f2bf(b.z), f2bf(b.w) };
        *(ushort4*)(xb + base)     = lo;
        *(ushort4*)(xb + base + 4) = hi;
    }
}

// ---------------------------------------------------------------------------
// conv_w: fp32 W (128x128, row-major [k][n]) -> bf16 swizzled
// Wsw[kg*1024 + n*8 + j] = W[(kg*8+j)*128 + n]   (kg = k/8, j = k%8)
// grid.y selects which W; 16384 threads per matrix.
// ---------------------------------------------------------------------------
__global__ void conv_w_kernel(const float* __restrict__ W0,
                              const float* __restrict__ W1,
                              const float* __restrict__ W2,
                              const float* __restrict__ W3,
                              unsigned short* __restrict__ Wsw)
{
    const float* Wm[4] = { W0, W1, W2, W3 };
    const float* __restrict__ W = Wm[blockIdx.y];
    unsigned short* __restrict__ o = Wsw + (size_t)blockIdx.y * 16384;

    int t = blockIdx.x * 256 + threadIdx.x;   // 0..16383
    int kg = t >> 7, n = t & 127;
    ushort4 p0, p1;
    p0.x = f2bf(W[(kg * 8 + 0) * 128 + n]);
    p0.y = f2bf(W[(kg * 8 + 1) * 128 + n]);
    p0.z = f2bf(W[(kg * 8 + 2) * 128 + n]);
    p0.w = f2bf(W[(kg * 8 + 3) * 128 + n]);
    p1.x = f2bf(W[(kg * 8 + 4) * 128 + n]);
    p1.y = f2bf(W[(kg * 8 + 5) * 128 + n]);
    p1.z = f2bf(W[(kg * 8 + 6) * 128 + n]);
    p1.w = f2bf(W[(kg * 8 + 7) * 128 + n]);
    *(ushort4*)(o + kg * 1024 + n * 8)     = p0;
    *(ushort4*)(o + kg * 1024 + n * 8 + 4) = p1;
}

// ---------------------------------------------------------------------------
// MFMA core: block tile 128(M) x 128(N) x 128(K), 256 threads / 4 waves,
// wave tile 64x64 = 4x4 of 16x16x32 bf16 MFMA.  K fully resident in LDS.
// A: row-major bf16, padded stride 136.  B: swizzled [kg][n][8], stride 1032.
// Layouts (m89/m120-verified): A lane: m=L&15, k=quad*8+j.
//                              B lane: k=quad*8+j, n=L&15.
//                              D lane/reg: m=quad*4+r, n=L&15.
// ---------------------------------------------------------------------------
__device__ __forceinline__ void mfma_tile_128(
    const unsigned short* __restrict__ A, const unsigned short* __restrict__ Bsw,
    unsigned short* As, unsigned short* Bs,
    int r0, int M, f32x4 (&acc)[4][4], int& mb, int& nb)
{
    const int t = threadIdx.x;
    #pragma unroll
    for (int it = 0; it < 8; it++) {
        int c   = t + it * 256;          // 0..2047
        int row = c >> 4, kp = c & 15;
        uint4 val = make_uint4(0, 0, 0, 0);
        if (r0 + row < M)
            val = *(const uint4*)(A + (size_t)(r0 + row) * 128 + kp * 8);
        *(uint4*)(As + row * 136 + kp * 8) = val;
    }
    #pragma unroll
    for (int it = 0; it < 8; it++) {
        int c  = t + it * 256;
        int kg = c >> 7, np = c & 127;
        *(uint4*)(Bs + kg * 1032 + np * 8) =
            *(const uint4*)(Bsw + kg * 1024 + np * 8);
    }
    __syncthreads();

    const int wave = t >> 6, L = t & 63;
    const int quad = L >> 4, l16 = L & 15;
    mb = (wave >> 1) * 64;
    nb = (wave & 1) * 64;

    #pragma unroll
    for (int a = 0; a < 4; a++)
        #pragma unroll
        for (int b = 0; b < 4; b++)
            #pragma unroll
            for (int e = 0; e < 4; e++) acc[a][b][e] = 0.f;

    #pragma unroll
    for (int kk = 0; kk < 4; kk++) {
        bf16x8 af[4], bf[4];
        #pragma unroll
        for (int mt = 0; mt < 4; mt++)
            af[mt] = *(const bf16x8*)(As + (mb + mt * 16 + l16) * 136
                                         + kk * 32 + quad * 8);
        #pragma unroll
        for (int nt = 0; nt < 4; nt++)
            bf[nt] = *(const bf16x8*)(Bs + (kk * 4 + quad) * 1032
                                         + (nb + nt * 16 + l16) * 8);
        #pragma unroll
        for (int mt = 0; mt < 4; mt++)
            #pragma unroll
            for (int nt = 0; nt < 4; nt++)
                acc[mt][nt] = __builtin_amdgcn_mfma_f32_16x16x32_bf16(
                    af[mt], bf[nt], acc[mt][nt], 0, 0, 0);
    }
}

// qkv: grid (gM, 3).  mode 0 -> q fp32, 1 -> k f16, 2 -> v bf16
__global__ __launch_bounds__(256) void qkv_mfma_kernel(
    const unsigned short* __restrict__ xb, const unsigned short* __restrict__ Wsw,
    float* __restrict__ q, unsigned short* __restrict__ kh,
    unsigned short* __restrict__ vh, int M)
{
    __shared__ __align__(16) unsigned short As[128 * 136];
    __shared__ __align__(16) unsigned short Bs[16 * 1032];
    const int mode = blockIdx.y;
    const int r0 = blockIdx.x * 128;

    f32x4 acc[4][4];
    int mb, nb;
    mfma_tile_128(xb, Wsw + (size_t)mode * 16384, As, Bs, r0, M, acc, mb, nb);

    const int L = threadIdx.x & 63, quad = L >> 4, l16 = L & 15;
    #pragma unroll
    for (int mt = 0; mt < 4; mt++) {
        #pragma unroll
        for (int nt = 0; nt < 4; nt++) {
            int col = nb + nt * 16 + l16;
            #pragma unroll
            for (int r = 0; r < 4; r++) {
                int row = r0 + mb + mt * 16 + quad * 4 + r;
                if (row < M) {
                    float val = acc[mt][nt][r];
                    if (mode == 0)      q[(size_t)row * 128 + col] = val;
                    else if (mode == 1) kh[(size_t)row * 128 + col] = f2h(val);
                    else                vh[(size_t)row * 128 + col] = f2bf(val);
                }
            }
        }
    }
}

// out: relu(aggh @ Wout + bout) + x
__global__ __launch_bounds__(256) void out_mfma_kernel(
    const unsigned short* __restrict__ aggh, const unsigned short* __restrict__ Wsw,
    const float* __restrict__ bout, const float* __restrict__ x,
    float* __restrict__ out, int M)
{
    __shared__ __align__(16) unsigned short As[128 * 136];
    __shared__ __align__(16) unsigned short Bs[16 * 1032];
    const int r0 = blockIdx.x * 128;

    f32x4 acc[4][4];
    int mb, nb;
    mfma_tile_128(aggh, Wsw, As, Bs, r0, M, acc, mb, nb);

    const int L = threadIdx.x & 63, quad = L >> 4, l16 = L & 15;
    #pragma unroll
    for (int mt = 0; mt < 4; mt++) {
        #pragma unroll
        for (int nt = 0; nt < 4; nt++) {
            int col = nb + nt * 16 + l16;
            float b = bout[col];
            #pragma unroll
            for (int r = 0; r < 4; r++) {
                int row = r0 + mb + mt * 16 + quad * 4 + r;
                if (row < M) {
                    float val = fmaxf(acc[mt][nt][r] + b, 0.f)
                              + x[(size_t)row * 128 + col];
                    out[(size_t)row * 128 + col] = val;
                }
            }
        }
    }
}

// ---------------------------------------------------------------------------
// CSR build: degree -> multi-block scan -> fill
// ---------------------------------------------------------------------------
__global__ void degree_kernel(const int* __restrict__ edge, int E,
                              int* __restrict__ deg)
{
    int e = blockIdx.x * 256 + threadIdx.x;
    if (e < E) atomicAdd(&deg[edge[E + e]], 1);
}

__global__ __launch_bounds__(256) void scan_local_kernel(
    const int* __restrict__ deg, int* __restrict__ locscan,
    int* __restrict__ bsum, int N)
{
    const int t = threadIdx.x, lane = t & 63, wid = t >> 6;
    const int i0 = blockIdx.x * 1024 + t * 4;
    __shared__ int wtot[4];

    int d0 = 0, d1 = 0, d2 = 0, d3 = 0;
    if (i0 + 3 < N) {
        int4 dv = *(const int4*)(deg + i0);
        d0 = dv.x; d1 = dv.y; d2 = dv.z; d3 = dv.w;
    } else {
        if (i0 < N)     d0 = deg[i0];
        if (i0 + 1 < N) d1 = deg[i0 + 1];
        if (i0 + 2 < N) d2 = deg[i0 + 2];
        if (i0 + 3 < N) d3 = deg[i0 + 3];
    }
    int s1 = d0 + d1, s2 = s1 + d2, s3 = s2 + d3;
    int tot = s3;

    int sc = tot;
    #pragma unroll
    for (int off = 1; off < 64; off <<= 1) {
        int n = __shfl_up(sc, off);
        if (lane >= off) sc += n;
    }
    if (lane == 63) wtot[wid] = sc;
    __syncthreads();

    int wof = 0;
    #pragma unroll
    for (int w = 0; w < 4; w++) wof += (w < wid) ? wtot[w] : 0;
    int pref = wof + sc - tot;

    if (i0 < N)     locscan[i0]     = pref + d0;
    if (i0 + 1 < N) locscan[i0 + 1] = pref + s1;
    if (i0 + 2 < N) locscan[i0 + 2] = pref + s2;
    if (i0 + 3 < N) locscan[i0 + 3] = pref + s3;
    if (t == 0) bsum[blockIdx.x] = wtot[0] + wtot[1] + wtot[2] + wtot[3];
}

__global__ __launch_bounds__(64) void scan_bsum_kernel(int* __restrict__ bsum,
                                                       int nb)
{
    const int lane = threadIdx.x;
    int run = 0;
    for (int b = 0; b < nb; b += 64) {
        int v = (b + lane < nb) ? bsum[b + lane] : 0;
        int sc = v;
        #pragma unroll
        for (int off = 1; off < 64; off <<= 1) {
            int n = __shfl_up(sc, off);
            if (lane >= off) sc += n;
        }
        if (b + lane < nb) bsum[b + lane] = run + sc - v;
        run += __shfl(sc, 63);
    }
}

__global__ void scan_final_kernel(const int* __restrict__ locscan,
                                  const int* __restrict__ bsum,
                                  int* __restrict__ rowptr, int N)
{
    int i = blockIdx.x * 256 + threadIdx.x;
    if (i < N) rowptr[i + 1] = locscan[i] + bsum[i >> 10];
    if (i == 0) rowptr[0] = 0;
}

__global__ void fill_kernel(const int* __restrict__ edge, int E,
                            const int* __restrict__ rowptr,
                            int* __restrict__ cnt, int* __restrict__ col)
{
    int e = blockIdx.x * 256 + threadIdx.x;
    if (e < E) {
        int dst = edge[E + e];
        int src = edge[e];
        int pos = atomicAdd(&cnt[dst], 1);
        col[rowptr[dst] + pos] = src;
    }
}

// q (f16 half2 regs) dot k-row segment (f16, 32 elems = 4 float4)
__device__ __forceinline__ float dot_qk(const float4* __restrict__ kp,
                                        const h2* qh)
{
    float a = 0.f;
    #pragma unroll
    for (int t = 0; t < 4; t++) {
        float4 kv = kp[t];
        const h2* hp = (const h2*)&kv;
#if __has_builtin(__builtin_amdgcn_fdot2)
        a = __builtin_amdgcn_fdot2(qh[4 * t + 0], hp[0], a, false);
        a = __builtin_amdgcn_fdot2(qh[4 * t + 1], hp[1], a, false);
        a = __builtin_amdgcn_fdot2(qh[4 * t + 2], hp[2], a, false);
        a = __builtin_amdgcn_fdot2(qh[4 * t + 3], hp[3], a, false);
#else
        #pragma unroll
        for (int u = 0; u < 4; u++) {
            h2 p = qh[4 * t + u] * hp[u];
            a += (float)p[0] + (float)p[1];
        }
#endif
    }
    return a;
}

// ---------------------------------------------------------------------------
// attn: 4 dst per 256-thread block, one wave each.  No LDS/barriers.
// h = lane&3 (head for scores), eo = lane>>2 (16 edges/chunk),
// hv = lane>>4 (head owning output dims 2*lane, 2*lane+1).
// k f16 (fdot2), v bf16, agg written bf16.
// ---------------------------------------------------------------------------
__global__ __launch_bounds__(256) void attn_kernel(
    const float* __restrict__ q, const unsigned short* __restrict__ kh,
    const unsigned short* __restrict__ vh,
    const int* __restrict__ rowptr, const int* __restrict__ col,
    float* __restrict__ scores, unsigned short* __restrict__ aggh, int N)
{
    const int wave = threadIdx.x >> 6;
    const int lane = threadIdx.x & 63;
    const int dst  = blockIdx.x * 4 + wave;
    if (dst >= N) return;

    const int start = rowptr[dst];
    const int deg   = rowptr[dst + 1] - start;
    const size_t orow = (size_t)dst * 128;

    if (deg == 0) {
        *(unsigned*)(aggh + orow + 2 * lane) = 0u;
        return;
    }

    const int h  = lane & 3;
    const int eo = lane >> 2;
    const int hv = lane >> 4;

    h2 qh[16];
    const float4* qp = (const float4*)(q + orow + h * HEAD_DIM);
    #pragma unroll
    for (int j = 0; j < 8; j++) {
        float4 qf = qp[j];
        qh[2 * j]     = h2{ (_Float16)qf.x, (_Float16)qf.y };
        qh[2 * j + 1] = h2{ (_Float16)qf.z, (_Float16)qf.w };
    }

    float m = -3.4e38f, dsum = 0.f, acc0 = 0.f, acc1 = 0.f;

    if (deg <= 64) {
        float sreg[4]; int creg[4];
        #pragma unroll
        for (int c = 0; c < 4; c++) {
            sreg[c] = -3.4e38f; creg[c] = 0;
            int le = c * 16 + eo;
            if (le < deg) {
                int src = col[start + le];
                creg[c] = src;
                sreg[c] = dot_qk(
                    (const float4*)(kh + (size_t)src * 128 + h * HEAD_DIM), qh);
            }
            m = fmaxf(m, sreg[c]);
        }
        #pragma unroll
        for (int off = 4; off < 64; off <<= 1)
            m = fmaxf(m, __shfl_xor(m, off));

        #pragma unroll
        for (int c = 0; c < 4; c++) {
            if (c * 16 < deg) {              // wave-uniform branch
                int le = c * 16 + eo;
                float ev = (le < deg) ? __expf(sreg[c] - m) : 0.f;
                dsum += ev;
                #pragma unroll
                for (int j = 0; j < 16; j++) {
                    int   sj = __shfl(creg[c], j * 4);
                    float w  = __shfl(ev, j * 4 + hv);
                    unsigned uv = *(const unsigned*)(vh + (size_t)sj * 128 + 2 * lane);
                    float2 vv = bf2f(uv);
                    acc0 = fmaf(w, vv.x, acc0);
                    acc1 = fmaf(w, vv.y, acc1);
                }
            }
        }
    } else {
        for (int base = 0; base < deg; base += 16) {
            int le = base + eo;
            float s = -3.4e38f;
            if (le < deg) {
                int src = col[start + le];
                s = dot_qk(
                    (const float4*)(kh + (size_t)src * 128 + h * HEAD_DIM), qh);
                scores[(size_t)(start + le) * 4 + h] = s;
            }
            m = fmaxf(m, s);
        }
        #pragma unroll
        for (int off = 4; off < 64; off <<= 1)
            m = fmaxf(m, __shfl_xor(m, off));

        for (int base = 0; base < deg; base += 16) {
            int le = base + eo;
            float ev = 0.f; int src = 0;
            if (le < deg) {
                ev  = __expf(scores[(size_t)(start + le) * 4 + h] - m);
                src = col[start + le];
            }
            dsum += ev;
            #pragma unroll
            for (int j = 0; j < 16; j++) {
                int   sj = __shfl(src, j * 4);
                float w  = __shfl(ev, j * 4 + hv);
                unsigned uv = *(const unsigned*)(vh + (size_t)sj * 128 + 2 * lane);
                float2 vv = bf2f(uv);
                acc0 = fmaf(w, vv.x, acc0);
                acc1 = fmaf(w, vv.y, acc1);
            }
        }
    }

    #pragma unroll
    for (int off = 4; off < 64; off <<= 1)
        dsum += __shfl_xor(dsum, off);
    float d = __shfl(dsum, hv);
    unsigned short lo = f2bf(acc0 / d);
    unsigned short hi = f2bf(acc1 / d);
    *(unsigned*)(aggh + orow + 2 * lane) = (unsigned)lo | ((unsigned)hi << 16);
}

// ---------------------------------------------------------------------------
extern "C" void kernel_launch(void* const* d_in, const int* in_sizes, int n_in,
                              void* d_out, int out_size, void* d_ws, size_t ws_size,
                              hipStream_t stream)
{
    const float* x    = (const float*)d_in[0];
    const int*   edge = (const int*)d_in[1];   // [2, E]
    const float* Wt   = (const float*)d_in[2];
    const float* Ws   = (const float*)d_in[3];
    const float* Wc   = (const float*)d_in[4];
    const float* Wout = (const float*)d_in[5];
    const float* bout = (const float*)d_in[6];
    float* out = (float*)d_out;

    const int N = in_sizes[0] / 128;
    const int E = in_sizes[1] / 2;

    // workspace: fp32, then ushort (bf16/f16), then ints
    float* q      = (float*)d_ws;
    float* scores = q + (size_t)N * 128;
    unsigned short* xb   = (unsigned short*)(scores + (size_t)E * 4);
    unsigned short* kh   = xb   + (size_t)N * 128;
    unsigned short* vh   = kh   + (size_t)N * 128;
    unsigned short* aggh = vh   + (size_t)N * 128;
    unsigned short* Wsw  = aggh + (size_t)N * 128;   // 4 * 16384 (qkv + out)
    int* rowptr  = (int*)(Wsw + 4 * 16384);
    int* deg     = rowptr + ((N + 1 + 3) & ~3);
    int* cnt     = deg + N;
    int* locscan = cnt + N;
    int* bsum    = locscan + N;
    int* colb    = bsum + 1024;

    hipMemsetAsync(deg, 0, (size_t)N * sizeof(int), stream);
    hipMemsetAsync(cnt, 0, (size_t)N * sizeof(int), stream);

    const int gM   = (N + 127) / 128;
    const int gE   = (E + 255) / 256;
    const int nb1k = (N + 1023) / 1024;
    const long xtot = (long)N * 128;

    conv_x_kernel<<<(int)((xtot / 8 + 255) / 256), 256, 0, stream>>>(x, xb, xtot);
    conv_w_kernel<<<dim3(64, 4), 256, 0, stream>>>(Wt, Ws, Wc, Wout, Wsw);
    qkv_mfma_kernel<<<dim3(gM, 3), 256, 0, stream>>>(xb, Wsw, q, kh, vh, N);
    degree_kernel<<<gE, 256, 0, stream>>>(edge, E, deg);
    scan_local_kernel<<<nb1k, 256, 0, stream>>>(deg, locscan, bsum, N);
    scan_bsum_kernel<<<1, 64, 0, stream>>>(bsum, nb1k);
    scan_final_kernel<<<(N + 255) / 256, 256, 0, stream>>>(locscan, bsum, rowptr, N);
    fill_kernel<<<gE, 256, 0, stream>>>(edge, E, rowptr, cnt, colb);
    attn_kernel<<<(N + 3) / 4, 256, 0, stream>>>(q, kh, vh, rowptr, colb,
                                                 scores, aggh, N);
    out_mfma_kernel<<<gM, 256, 0, stream>>>(aggh, Wsw + 3 * 16384, bout, x, out, N);
}

// Round 6
// 302.871 us; speedup vs baseline: 1.5041x; 1.0213x over previous
//
#include <hip/hip_runtime.h>
#include <hip/hip_bf16.h>

#define HEADS 4
#define HEAD_DIM 32

typedef __bf16 bf16x8 __attribute__((ext_vector_type(8)));
typedef float  f32x4  __attribute__((ext_vector_type(4)));
typedef _Float16 h2   __attribute__((ext_vector_type(2)));

// float -> bf16 (RNE)
__device__ __forceinline__ unsigned short f2bf(float f) {
    unsigned u = __float_as_uint(f);
    u += 0x7fffu + ((u >> 16) & 1u);
    return (unsigned short)(u >> 16);
}
__device__ __forceinline__ unsigned pack2bf(float a, float b) {
    return (unsigned)f2bf(a) | ((unsigned)f2bf(b) << 16);
}
// uint32 bf16 pair {elem 2i (lo16), 2i+1 (hi16)} -> floats
__device__ __forceinline__ float2 bf2f(unsigned u) {
    return make_float2(__uint_as_float(u << 16),
                       __uint_as_float(u & 0xffff0000u));
}
__device__ __forceinline__ unsigned short f2h(float f) {
    _Float16 h = (_Float16)f;
    return *(unsigned short*)&h;
}

// ---------------------------------------------------------------------------
// prep: blocks 0..31 -> conv_w (4 matrices x 2048 threads, fp32 -> bf16
// swizzled, kg strictly 0..15 — NO overrun); blocks >=32 -> degree count.
// Wsw[m][kg*1024 + n*8 + j] = W[(kg*8+j)*128 + n]
// ---------------------------------------------------------------------------
__global__ __launch_bounds__(256) void prep_kernel(
    const float* __restrict__ W0, const float* __restrict__ W1,
    const float* __restrict__ W2, const float* __restrict__ W3,
    unsigned short* __restrict__ Wsw,
    const int* __restrict__ edge, int E, int* __restrict__ deg)
{
    if (blockIdx.x < 32) {
        const float* Wm[4] = { W0, W1, W2, W3 };
        int mi = blockIdx.x >> 3;                        // 0..3
        const float* __restrict__ W = Wm[mi];
        unsigned short* __restrict__ o = Wsw + (size_t)mi * 16384;
        int t = (blockIdx.x & 7) * 256 + threadIdx.x;    // 0..2047
        int kg = t >> 7;                                 // 0..15
        int n  = t & 127;                                // 0..127
        ushort4 p0, p1;
        p0.x = f2bf(W[(kg * 8 + 0) * 128 + n]);
        p0.y = f2bf(W[(kg * 8 + 1) * 128 + n]);
        p0.z = f2bf(W[(kg * 8 + 2) * 128 + n]);
        p0.w = f2bf(W[(kg * 8 + 3) * 128 + n]);
        p1.x = f2bf(W[(kg * 8 + 4) * 128 + n]);
        p1.y = f2bf(W[(kg * 8 + 5) * 128 + n]);
        p1.z = f2bf(W[(kg * 8 + 6) * 128 + n]);
        p1.w = f2bf(W[(kg * 8 + 7) * 128 + n]);
        *(ushort4*)(o + kg * 1024 + n * 8)     = p0;
        *(ushort4*)(o + kg * 1024 + n * 8 + 4) = p1;
    } else {
        int e = (blockIdx.x - 32) * 256 + threadIdx.x;
        if (e < E) atomicAdd(&deg[edge[E + e]], 1);
    }
}

// ---------------------------------------------------------------------------
// MFMA helpers: block tile 128x128x128, 256 thr / 4 waves, wave tile 64x64.
// As: row-major bf16, padded stride 136.  Bs: swizzled [kg][n][8], stride 1032.
// ---------------------------------------------------------------------------
__device__ __forceinline__ void stage_B(const unsigned short* __restrict__ Bsw,
                                        unsigned short* Bs, int t)
{
    #pragma unroll
    for (int it = 0; it < 8; it++) {
        int c  = t + it * 256;
        int kg = c >> 7, np = c & 127;
        *(uint4*)(Bs + kg * 1032 + np * 8) =
            *(const uint4*)(Bsw + kg * 1024 + np * 8);
    }
}

__device__ __forceinline__ void mfma_compute(
    const unsigned short* As, const unsigned short* Bs,
    f32x4 (&acc)[4][4], int& mb, int& nb, int t)
{
    const int wave = t >> 6, L = t & 63;
    const int quad = L >> 4, l16 = L & 15;
    mb = (wave >> 1) * 64;
    nb = (wave & 1) * 64;

    #pragma unroll
    for (int a = 0; a < 4; a++)
        #pragma unroll
        for (int b = 0; b < 4; b++)
            #pragma unroll
            for (int e = 0; e < 4; e++) acc[a][b][e] = 0.f;

    #pragma unroll
    for (int kk = 0; kk < 4; kk++) {
        bf16x8 af[4], bf[4];
        #pragma unroll
        for (int mt = 0; mt < 4; mt++)
            af[mt] = *(const bf16x8*)(As + (mb + mt * 16 + l16) * 136
                                         + kk * 32 + quad * 8);
        #pragma unroll
        for (int nt = 0; nt < 4; nt++)
            bf[nt] = *(const bf16x8*)(Bs + (kk * 4 + quad) * 1032
                                         + (nb + nt * 16 + l16) * 8);
        #pragma unroll
        for (int mt = 0; mt < 4; mt++)
            #pragma unroll
            for (int nt = 0; nt < 4; nt++)
                acc[mt][nt] = __builtin_amdgcn_mfma_f32_16x16x32_bf16(
                    af[mt], bf[nt], acc[mt][nt], 0, 0, 0);
    }
}

// qkv: A staged from fp32 x (converted to bf16 at LDS write).
// grid (gM, 3): mode 0 -> q fp32, 1 -> k f16, 2 -> v bf16
__global__ __launch_bounds__(256) void qkv_mfma_kernel(
    const float* __restrict__ x, const unsigned short* __restrict__ Wsw,
    float* __restrict__ q, unsigned short* __restrict__ kh,
    unsigned short* __restrict__ vh, int M)
{
    __shared__ __align__(16) unsigned short As[128 * 136];
    __shared__ __align__(16) unsigned short Bs[16 * 1032];
    const int mode = blockIdx.y;
    const int r0 = blockIdx.x * 128;
    const int t  = threadIdx.x;

    #pragma unroll
    for (int it = 0; it < 8; it++) {
        int c   = t + it * 256;          // 0..2047
        int row = c >> 4, kp = c & 15;   // 8 bf16 elems per thread
        float4 a = make_float4(0.f, 0.f, 0.f, 0.f);
        float4 b = make_float4(0.f, 0.f, 0.f, 0.f);
        if (r0 + row < M) {
            a = *(const float4*)(x + (size_t)(r0 + row) * 128 + kp * 8);
            b = *(const float4*)(x + (size_t)(r0 + row) * 128 + kp * 8 + 4);
        }
        uint4 pk;
        pk.x = pack2bf(a.x, a.y);
        pk.y = pack2bf(a.z, a.w);
        pk.z = pack2bf(b.x, b.y);
        pk.w = pack2bf(b.z, b.w);
        *(uint4*)(As + row * 136 + kp * 8) = pk;
    }
    stage_B(Wsw + (size_t)mode * 16384, Bs, t);
    __syncthreads();

    f32x4 acc[4][4];
    int mb, nb;
    mfma_compute(As, Bs, acc, mb, nb, t);

    const int L = t & 63, quad = L >> 4, l16 = L & 15;
    #pragma unroll
    for (int mt = 0; mt < 4; mt++) {
        #pragma unroll
        for (int nt = 0; nt < 4; nt++) {
            int col = nb + nt * 16 + l16;
            #pragma unroll
            for (int r = 0; r < 4; r++) {
                int row = r0 + mb + mt * 16 + quad * 4 + r;
                if (row < M) {
                    float val = acc[mt][nt][r];
                    if (mode == 0)      q[(size_t)row * 128 + col] = val;
                    else if (mode == 1) kh[(size_t)row * 128 + col] = f2h(val);
                    else                vh[(size_t)row * 128 + col] = f2bf(val);
                }
            }
        }
    }
}

// out: relu(aggh @ Wout + bout) + x    (A staged from bf16 aggh)
__global__ __launch_bounds__(256) void out_mfma_kernel(
    const unsigned short* __restrict__ aggh, const unsigned short* __restrict__ Wsw,
    const float* __restrict__ bout, const float* __restrict__ x,
    float* __restrict__ out, int M)
{
    __shared__ __align__(16) unsigned short As[128 * 136];
    __shared__ __align__(16) unsigned short Bs[16 * 1032];
    const int r0 = blockIdx.x * 128;
    const int t  = threadIdx.x;

    #pragma unroll
    for (int it = 0; it < 8; it++) {
        int c   = t + it * 256;
        int row = c >> 4, kp = c & 15;
        uint4 val = make_uint4(0, 0, 0, 0);
        if (r0 + row < M)
            val = *(const uint4*)(aggh + (size_t)(r0 + row) * 128 + kp * 8);
        *(uint4*)(As + row * 136 + kp * 8) = val;
    }
    stage_B(Wsw, Bs, t);
    __syncthreads();

    f32x4 acc[4][4];
    int mb, nb;
    mfma_compute(As, Bs, acc, mb, nb, t);

    const int L = t & 63, quad = L >> 4, l16 = L & 15;
    #pragma unroll
    for (int mt = 0; mt < 4; mt++) {
        #pragma unroll
        for (int nt = 0; nt < 4; nt++) {
            int col = nb + nt * 16 + l16;
            float b = bout[col];
            #pragma unroll
            for (int r = 0; r < 4; r++) {
                int row = r0 + mb + mt * 16 + quad * 4 + r;
                if (row < M) {
                    float val = fmaxf(acc[mt][nt][r] + b, 0.f)
                              + x[(size_t)row * 128 + col];
                    out[(size_t)row * 128 + col] = val;
                }
            }
        }
    }
}

// ---------------------------------------------------------------------------
// CSR scan chain + fill
// ---------------------------------------------------------------------------
__global__ __launch_bounds__(256) void scan_local_kernel(
    const int* __restrict__ deg, int* __restrict__ locscan,
    int* __restrict__ bsum, int N)
{
    const int t = threadIdx.x, lane = t & 63, wid = t >> 6;
    const int i0 = blockIdx.x * 1024 + t * 4;
    __shared__ int wtot[4];

    int d0 = 0, d1 = 0, d2 = 0, d3 = 0;
    if (i0 + 3 < N) {
        int4 dv = *(const int4*)(deg + i0);
        d0 = dv.x; d1 = dv.y; d2 = dv.z; d3 = dv.w;
    } else {
        if (i0 < N)     d0 = deg[i0];
        if (i0 + 1 < N) d1 = deg[i0 + 1];
        if (i0 + 2 < N) d2 = deg[i0 + 2];
        if (i0 + 3 < N) d3 = deg[i0 + 3];
    }
    int s1 = d0 + d1, s2 = s1 + d2, s3 = s2 + d3;
    int tot = s3;

    int sc = tot;
    #pragma unroll
    for (int off = 1; off < 64; off <<= 1) {
        int n = __shfl_up(sc, off);
        if (lane >= off) sc += n;
    }
    if (lane == 63) wtot[wid] = sc;
    __syncthreads();

    int wof = 0;
    #pragma unroll
    for (int w = 0; w < 4; w++) wof += (w < wid) ? wtot[w] : 0;
    int pref = wof + sc - tot;

    if (i0 < N)     locscan[i0]     = pref + d0;
    if (i0 + 1 < N) locscan[i0 + 1] = pref + s1;
    if (i0 + 2 < N) locscan[i0 + 2] = pref + s2;
    if (i0 + 3 < N) locscan[i0 + 3] = pref + s3;
    if (t == 0) bsum[blockIdx.x] = wtot[0] + wtot[1] + wtot[2] + wtot[3];
}

__global__ __launch_bounds__(64) void scan_bsum_kernel(int* __restrict__ bsum,
                                                       int nb)
{
    const int lane = threadIdx.x;
    int run = 0;
    for (int b = 0; b < nb; b += 64) {
        int v = (b + lane < nb) ? bsum[b + lane] : 0;
        int sc = v;
        #pragma unroll
        for (int off = 1; off < 64; off <<= 1) {
            int n = __shfl_up(sc, off);
            if (lane >= off) sc += n;
        }
        if (b + lane < nb) bsum[b + lane] = run + sc - v;
        run += __shfl(sc, 63);
    }
}

__global__ void scan_final_kernel(const int* __restrict__ locscan,
                                  const int* __restrict__ bsum,
                                  int* __restrict__ rowptr, int N)
{
    int i = blockIdx.x * 256 + threadIdx.x;
    if (i < N) rowptr[i + 1] = locscan[i] + bsum[i >> 10];
    if (i == 0) rowptr[0] = 0;
}

__global__ void fill_kernel(const int* __restrict__ edge, int E,
                            const int* __restrict__ rowptr,
                            int* __restrict__ cnt, int* __restrict__ col)
{
    int e = blockIdx.x * 256 + threadIdx.x;
    if (e < E) {
        int dst = edge[E + e];
        int src = edge[e];
        int pos = atomicAdd(&cnt[dst], 1);
        col[rowptr[dst] + pos] = src;
    }
}

// q (h2 regs) dot k-row segment (f16, global gather) — general path only
__device__ __forceinline__ float dot_qk(const float4* __restrict__ kp,
                                        const h2* qh)
{
    float a = 0.f;
    #pragma unroll
    for (int t = 0; t < 4; t++) {
        float4 kv = kp[t];
        const h2* hp = (const h2*)&kv;
#if __has_builtin(__builtin_amdgcn_fdot2)
        a = __builtin_amdgcn_fdot2(qh[4 * t + 0], hp[0], a, false);
        a = __builtin_amdgcn_fdot2(qh[4 * t + 1], hp[1], a, false);
        a = __builtin_amdgcn_fdot2(qh[4 * t + 2], hp[2], a, false);
        a = __builtin_amdgcn_fdot2(qh[4 * t + 3], hp[3], a, false);
#else
        #pragma unroll
        for (int u = 0; u < 4; u++) {
            h2 p = qh[4 * t + u] * hp[u];
            a += (float)p[0] + (float)p[1];
        }
#endif
    }
    return a;
}

// ---------------------------------------------------------------------------
// attn: 4 dst per 256-thread block, one wave each.
// Fast path (deg<=64): k rows staged into LDS with COALESCED loads
// (64 lanes x 16B = 4 full 256B rows per instruction), per-lane dot from LDS.
// v-pass weights/srcs broadcast via per-wave LDS (conflict-free).
// Same-wave LDS write->read needs no barrier (in-order per wave).
// h = lane&3 (head), eo = lane>>2 (edge in chunk), hv = lane>>4 (output head).
// ---------------------------------------------------------------------------
__global__ __launch_bounds__(256) void attn_kernel(
    const float* __restrict__ q, const unsigned short* __restrict__ kh,
    const unsigned short* __restrict__ vh,
    const int* __restrict__ rowptr, const int* __restrict__ col,
    float* __restrict__ scores, unsigned short* __restrict__ aggh, int N)
{
    const int wv   = threadIdx.x >> 6;
    const int lane = threadIdx.x & 63;
    const int dst  = blockIdx.x * 4 + wv;
    if (dst >= N) return;

    __shared__ __align__(16) unsigned short kbuf[4][16 * 136];
    __shared__ __align__(16) float swW[4][64];
    __shared__ __align__(16) int   swS[4][16];

    const int start = rowptr[dst];
    const int deg   = rowptr[dst + 1] - start;
    const size_t orow = (size_t)dst * 128;

    if (deg == 0) {
        *(unsigned*)(aggh + orow + 2 * lane) = 0u;
        return;
    }

    const int h  = lane & 3;
    const int eo = lane >> 2;
    const int hv = lane >> 4;

    h2 qh[16];
    {
        const float4* qp = (const float4*)(q + orow + h * HEAD_DIM);
        #pragma unroll
        for (int j = 0; j < 8; j++) {
            float4 qf = qp[j];
            qh[2 * j]     = h2{ (_Float16)qf.x, (_Float16)qf.y };
            qh[2 * j + 1] = h2{ (_Float16)qf.z, (_Float16)qf.w };
        }
    }

    float m = -3.4e38f, dsum = 0.f, acc0 = 0.f, acc1 = 0.f;

    if (deg <= 64) {
        float sreg[4]; int creg[4];
        #pragma unroll
        for (int c = 0; c < 4; c++) {
            sreg[c] = -3.4e38f; creg[c] = 0;
            if (c * 16 < deg) {                         // wave-uniform
                int nle = deg - c * 16;                 // edges in this chunk (eo<16 caps)
                int src_l = 0;
                if (lane < 16 && lane < nle)
                    src_l = col[start + c * 16 + lane];
                creg[c] = src_l;
                // coalesced stage: 4 rows per instruction
                #pragma unroll
                for (int i = 0; i < 4; i++) {
                    int r  = i * 4 + (lane >> 4);
                    int sr = __shfl(src_l, r);
                    uint4 kv = *(const uint4*)(kh + (size_t)sr * 128 + (lane & 15) * 8);
                    *(uint4*)(&kbuf[wv][r * 136 + (lane & 15) * 8]) = kv;
                }
                // per-lane dot from LDS: edge eo, head h
                if (eo < nle) {
                    const unsigned short* kb = &kbuf[wv][eo * 136 + h * 32];
                    uint4 u0 = *(const uint4*)(kb);
                    uint4 u1 = *(const uint4*)(kb + 8);
                    uint4 u2 = *(const uint4*)(kb + 16);
                    uint4 u3 = *(const uint4*)(kb + 24);
                    const h2* p0 = (const h2*)&u0;
                    const h2* p1 = (const h2*)&u1;
                    const h2* p2 = (const h2*)&u2;
                    const h2* p3 = (const h2*)&u3;
                    float a = 0.f;
                    #pragma unroll
                    for (int j = 0; j < 4; j++) {
#if __has_builtin(__builtin_amdgcn_fdot2)
                        a = __builtin_amdgcn_fdot2(qh[j],      p0[j], a, false);
                        a = __builtin_amdgcn_fdot2(qh[4 + j],  p1[j], a, false);
                        a = __builtin_amdgcn_fdot2(qh[8 + j],  p2[j], a, false);
                        a = __builtin_amdgcn_fdot2(qh[12 + j], p3[j], a, false);
#else
                        h2 w0 = qh[j] * p0[j], w1 = qh[4+j] * p1[j];
                        h2 w2 = qh[8+j] * p2[j], w3 = qh[12+j] * p3[j];
                        a += (float)w0[0] + (float)w0[1] + (float)w1[0] + (float)w1[1]
                           + (float)w2[0] + (float)w2[1] + (float)w3[0] + (float)w3[1];
#endif
                    }
                    sreg[c] = a;
                }
                m = fmaxf(m, sreg[c]);
            }
        }
        #pragma unroll
        for (int off = 4; off < 64; off <<= 1)
            m = fmaxf(m, __shfl_xor(m, off));

        #pragma unroll
        for (int c = 0; c < 4; c++) {
            if (c * 16 < deg) {                         // wave-uniform
                int nle = deg - c * 16;
                float ev = (eo < nle) ? __expf(sreg[c] - m) : 0.f;
                dsum += ev;
                swW[wv][lane] = ev;
                if (lane < 16) swS[wv][lane] = creg[c];
                int4 s0 = *(const int4*)&swS[wv][0];
                int4 s1 = *(const int4*)&swS[wv][4];
                int4 s2 = *(const int4*)&swS[wv][8];
                int4 s3 = *(const int4*)&swS[wv][12];
                int sj[16] = { s0.x, s0.y, s0.z, s0.w, s1.x, s1.y, s1.z, s1.w,
                               s2.x, s2.y, s2.z, s2.w, s3.x, s3.y, s3.z, s3.w };
                #pragma unroll
                for (int j = 0; j < 16; j++) {
                    float w = swW[wv][j * 4 + hv];
                    unsigned uv = *(const unsigned*)(vh + (size_t)sj[j] * 128 + 2 * lane);
                    float2 vvv = bf2f(uv);
                    acc0 = fmaf(w, vvv.x, acc0);
                    acc1 = fmaf(w, vvv.y, acc1);
                }
            }
        }
    } else {
        // ---- general path (rare): direct gathers + global scores ----
        for (int base = 0; base < deg; base += 16) {
            int le = base + eo;
            float s = -3.4e38f;
            if (le < deg) {
                int src = col[start + le];
                s = dot_qk(
                    (const float4*)(kh + (size_t)src * 128 + h * HEAD_DIM), qh);
                scores[(size_t)(start + le) * 4 + h] = s;
            }
            m = fmaxf(m, s);
        }
        #pragma unroll
        for (int off = 4; off < 64; off <<= 1)
            m = fmaxf(m, __shfl_xor(m, off));

        for (int base = 0; base < deg; base += 16) {
            int le = base + eo;
            float ev = 0.f; int src = 0;
            if (le < deg) {
                ev  = __expf(scores[(size_t)(start + le) * 4 + h] - m);
                src = col[start + le];
            }
            dsum += ev;
            swW[wv][lane] = ev;
            if (h == 0) swS[wv][eo] = src;
            int4 s0 = *(const int4*)&swS[wv][0];
            int4 s1 = *(const int4*)&swS[wv][4];
            int4 s2 = *(const int4*)&swS[wv][8];
            int4 s3 = *(const int4*)&swS[wv][12];
            int sj[16] = { s0.x, s0.y, s0.z, s0.w, s1.x, s1.y, s1.z, s1.w,
                           s2.x, s2.y, s2.z, s2.w, s3.x, s3.y, s3.z, s3.w };
            #pragma unroll
            for (int j = 0; j < 16; j++) {
                float w = swW[wv][j * 4 + hv];
                unsigned uv = *(const unsigned*)(vh + (size_t)sj[j] * 128 + 2 * lane);
                float2 vvv = bf2f(uv);
                acc0 = fmaf(w, vvv.x, acc0);
                acc1 = fmaf(w, vvv.y, acc1);
            }
        }
    }

    #pragma unroll
    for (int off = 4; off < 64; off <<= 1)
        dsum += __shfl_xor(dsum, off);
    float d = __shfl(dsum, hv);
    unsigned short lo = f2bf(acc0 / d);
    unsigned short hi = f2bf(acc1 / d);
    *(unsigned*)(aggh + orow + 2 * lane) = (unsigned)lo | ((unsigned)hi << 16);
}

// ---------------------------------------------------------------------------
extern "C" void kernel_launch(void* const* d_in, const int* in_sizes, int n_in,
                              void* d_out, int out_size, void* d_ws, size_t ws_size,
                              hipStream_t stream)
{
    const float* x    = (const float*)d_in[0];
    const int*   edge = (const int*)d_in[1];   // [2, E]
    const float* Wt   = (const float*)d_in[2];
    const float* Ws   = (const float*)d_in[3];
    const float* Wc   = (const float*)d_in[4];
    const float* Wout = (const float*)d_in[5];
    const float* bout = (const float*)d_in[6];
    float* out = (float*)d_out;

    const int N = in_sizes[0] / 128;
    const int E = in_sizes[1] / 2;

    // workspace: fp32, then ushort (bf16/f16), then ints
    float* q      = (float*)d_ws;
    float* scores = q + (size_t)N * 128;
    unsigned short* kh   = (unsigned short*)(scores + (size_t)E * 4);
    unsigned short* vh   = kh   + (size_t)N * 128;
    unsigned short* aggh = vh   + (size_t)N * 128;
    unsigned short* Wsw  = aggh + (size_t)N * 128;   // 4 * 16384
    int* rowptr  = (int*)(Wsw + 4 * 16384);
    int* deg     = rowptr + ((N + 1 + 3) & ~3);
    int* cnt     = deg + N;                          // contiguous with deg
    int* locscan = cnt + N;
    int* bsum    = locscan + N;
    int* colb    = bsum + 1024;

    hipMemsetAsync(deg, 0, 2 * (size_t)N * sizeof(int), stream);  // deg + cnt

    const int gM   = (N + 127) / 128;
    const int gE   = (E + 255) / 256;
    const int nb1k = (N + 1023) / 1024;

    prep_kernel<<<32 + gE, 256, 0, stream>>>(Wt, Ws, Wc, Wout, Wsw, edge, E, deg);
    qkv_mfma_kernel<<<dim3(gM, 3), 256, 0, stream>>>(x, Wsw, q, kh, vh, N);
    scan_local_kernel<<<nb1k, 256, 0, stream>>>(deg, locscan, bsum, N);
    scan_bsum_kernel<<<1, 64, 0, stream>>>(bsum, nb1k);
    scan_final_kernel<<<(N + 255) / 256, 256, 0, stream>>>(locscan, bsum, rowptr, N);
    fill_kernel<<<gE, 256, 0, stream>>>(edge, E, rowptr, cnt, colb);
    attn_kernel<<<(N + 3) / 4, 256, 0, stream>>>(q, kh, vh, rowptr, colb,
                                                 scores, aggh, N);
    out_mfma_kernel<<<gM, 256, 0, stream>>>(aggh, Wsw + 3 * 16384, bout, x, out, N);
}